// Round 2
// baseline (9.816 us; speedup 1.0000x reference)
//
#include <hip/hip_runtime.h>
#include <math.h>

#define NUM_STEPS   3
#define NUM_POINTS  16
#define IN_CH       64
#define OUT_CH      256

// Algebraic collapse: the 256-wide out-channel broadcast is redundant in the
// reference (no out-channel-dependent parameter), so
//   out[n, o] == sum_c x_final[n, c]  for all o.
// Total traffic: 1 MB read + 4 MB write  -> ~0.8 us at 6.3 TB/s; the measured
// ~10 us is dispatch/replay overhead, so this round maximizes per-thread work
// to test whether kernel GPU time contributes at all.
//
// Layout: each thread loads ONE float4 (4 consecutive channels of one row,
// 16 B/lane fully coalesced). 16 threads cover a 64-channel row; a 256-thread
// block covers 16 rows; grid = 4096/16 = 256 blocks.
__global__ __launch_bounds__(256)
void flow_kernel(const float4* __restrict__ data4,
                 const float* __restrict__ angles,
                 const float* __restrict__ velo,
                 float4* __restrict__ out4,
                 int nrows) {
    __shared__ float s_vcos[NUM_POINTS];
    __shared__ float s_vsin[NUM_POINTS];

    const int tid = threadIdx.x;
    if (tid < NUM_POINTS) {
        const float a = angles[tid];
        const float v = velo[tid];
        s_vcos[tid] = v * cosf(a);   // t-independent term
        s_vsin[tid] = v * sinf(a);   // multiplied by t
    }
    __syncthreads();

    const int gidx = blockIdx.x * 256 + tid;   // one float4 of data per thread
    const int row  = gidx >> 4;                // 16 threads per row
    const int cg   = gidx & 15;                // channel-group within row
    if (row >= nrows) return;

    const float4 xv = data4[gidx];
    float xs[4] = {xv.x, xv.y, xv.z, xv.w};

    float part = 0.0f;
#pragma unroll
    for (int k = 0; k < 4; ++k) {
        float x = xs[k];
#pragma unroll
        for (int s = 0; s < NUM_STEPS; ++s) {
            const float t = tanhf(x);
            // jnp.round == round-half-to-even == rintf
            int pos = (int)rintf((1.0f + t) * (NUM_POINTS * 0.5f));
            pos = min(max(pos, 0), NUM_POINTS - 1);
            const float st = s_vcos[pos] + t * s_vsin[pos];
            x += st / (float)NUM_STEPS;
        }
        part += x;
    }

    // reduce across the 16 lanes of this row (xor masks 1,2,4,8 stay in-group)
#pragma unroll
    for (int off = 1; off < 16; off <<= 1) {
        part += __shfl_xor(part, off);
    }

    // broadcast-store 256 identical floats per row: each of the 16 lanes
    // writes 4 float4s -> 4 x 256 B contiguous segments per row, coalesced
    const float4 v4 = make_float4(part, part, part, part);
#pragma unroll
    for (int k = 0; k < 4; ++k) {
        out4[(size_t)row * (OUT_CH / 4) + cg + 16 * k] = v4;
    }
}

extern "C" void kernel_launch(void* const* d_in, const int* in_sizes, int n_in,
                              void* d_out, int out_size, void* d_ws, size_t ws_size,
                              hipStream_t stream) {
    const float* data   = (const float*)d_in[0];
    const float* angles = (const float*)d_in[1];
    const float* velo   = (const float*)d_in[2];
    float* out = (float*)d_out;

    const int nrows = in_sizes[0] / IN_CH;            // 4096
    const int total_threads = nrows * (IN_CH / 4);    // one float4 per thread
    const int grid = (total_threads + 255) / 256;     // 256 blocks

    flow_kernel<<<grid, 256, 0, stream>>>(
        (const float4*)data, angles, velo, (float4*)out, nrows);
}